// Round 1
// baseline (735.810 us; speedup 1.0000x reference)
//
#include <hip/hip_runtime.h>
#include <stdint.h>

#define N_PTS 1000000
#define FIN   64
#define HID   32
#define GB    2
#define GX    512
#define GY    512
#define GZ    64
#define KMAX  128
#define NBUCKET 4096
#define BITS_LO 0x3E4CCCCDu   /* bits of 0.2f */
#define BUCKET_SHIFT 13
#define CAND_CAP 4096

#define GRID_CELLS ((size_t)GB*GX*GY*GZ)          /* 33,554,432 */
#define GRID_BYTES (GRID_CELLS*4)                  /* 134,217,728 */
#define HIST_OFF   GRID_BYTES
#define HIST_BYTES (NBUCKET*4)
#define CNT_OFF    (HIST_OFF + HIST_BYTES)
#define CNT_BYTES  64
#define KEYS_OFF   (CNT_OFF + CNT_BYTES)
#define KEYS_BYTES ((size_t)N_PTS*8)
#define CAND_OFF   (KEYS_OFF + KEYS_BYTES)
#define CLEAR_BYTES (KEYS_OFF)                     /* grid + hist + counters */

/* counters: [0]=peak count M, [1]=collect count C, [2]=cutoff bucket, [3]=mask-is-bytes flag */

__global__ void k_detect_mask(const int* __restrict__ mask_i, unsigned int* __restrict__ counters) {
    if (threadIdx.x == 0 && blockIdx.x == 0) {
        unsigned int flag = 0;
        for (int k = 0; k < 256; ++k) {
            unsigned int v = (unsigned int)mask_i[k];
            if (v > 1u) flag = 1u;
        }
        counters[3] = flag;
    }
}

__global__ __launch_bounds__(256) void k_mlp(
    const float* __restrict__ feats,
    const int* __restrict__ cb, const int* __restrict__ cx,
    const int* __restrict__ cy, const int* __restrict__ cz,
    const int* __restrict__ mask_i,
    const float* __restrict__ W1, const float* __restrict__ b1,
    const float* __restrict__ W2, const float* __restrict__ b2,
    float* __restrict__ score_out, unsigned int* __restrict__ grid,
    const unsigned int* __restrict__ counters)
{
    int i = blockIdx.x * 256 + threadIdx.x;
    if (i >= N_PTS) return;

    float f[FIN];
    const float4* rp = (const float4*)(feats + (size_t)i * FIN);
#pragma unroll
    for (int q = 0; q < FIN / 4; ++q) {
        float4 v = rp[q];
        f[4*q+0] = v.x; f[4*q+1] = v.y; f[4*q+2] = v.z; f[4*q+3] = v.w;
    }

    float hj[HID];
#pragma unroll
    for (int j = 0; j < HID; ++j) hj[j] = b1[j];

#pragma unroll 4
    for (int k = 0; k < FIN; ++k) {
        float fk = f[k];
#pragma unroll
        for (int j = 0; j < HID; ++j) hj[j] = fmaf(fk, W1[k*HID + j], hj[j]);
    }

    float x = b2[0];
#pragma unroll
    for (int j = 0; j < HID; ++j) x += fmaxf(hj[j], 0.0f) * W2[j];

    float s = 1.0f / (1.0f + expf(-x));

    unsigned int mflag = counters[3];
    bool mk;
    if (mflag) mk = ((const unsigned char*)mask_i)[i] != 0;
    else       mk = mask_i[i] != 0;
    if (!mk) s = 0.0f;

    score_out[i] = s;

    if (s > 0.1f) {
        unsigned int sb = __float_as_uint(s);
        int b = cb[i], xx = cx[i], yy = cy[i], zz = cz[i];
        size_t cell = (((size_t)((b*GX + xx)*GY + yy)) << 6) + (size_t)zz;
        atomicMax(&grid[cell], sb);
    }
}

__global__ __launch_bounds__(256) void k_peak(
    const float* __restrict__ s_buf,
    const int* __restrict__ cb, const int* __restrict__ cx,
    const int* __restrict__ cy, const int* __restrict__ cz,
    const unsigned int* __restrict__ grid,
    unsigned long long* __restrict__ keys,
    unsigned int* __restrict__ counters,
    unsigned int* __restrict__ hist)
{
    int i = blockIdx.x * 256 + threadIdx.x;
    if (i >= N_PTS) return;
    float s = s_buf[i];
    if (!(s > 0.2f)) return;
    unsigned int sb = __float_as_uint(s);
    int b = cb[i], x = cx[i], y = cy[i], z = cz[i];
    int z0 = (z > 0) ? z - 1 : 0;
    int z1 = (z < GZ-1) ? z + 1 : GZ-1;

    bool peak = true;
    for (int dx = -1; dx <= 1 && peak; ++dx) {
        int xx = x + dx;
        if ((unsigned)xx >= (unsigned)GX) continue;
        for (int dy = -1; dy <= 1 && peak; ++dy) {
            int yy = y + dy;
            if ((unsigned)yy >= (unsigned)GY) continue;
            const unsigned int* cell = grid + (((size_t)((b*GX + xx)*GY + yy)) << 6);
            for (int zz = z0; zz <= z1; ++zz) {
                if (cell[zz] > sb) { peak = false; break; }
            }
        }
    }
    if (!peak) return;

    unsigned int pos = atomicAdd(&counters[0], 1u);
    keys[pos] = ((unsigned long long)sb << 32) | (unsigned int)(~(unsigned int)i);
    unsigned int bucket = (sb - BITS_LO) >> BUCKET_SHIFT;
    if (bucket > NBUCKET - 1u) bucket = NBUCKET - 1u;
    atomicAdd(&hist[bucket], 1u);
}

__global__ __launch_bounds__(256) void k_cutoff(
    const unsigned int* __restrict__ hist, unsigned int* __restrict__ counters)
{
    __shared__ unsigned int lh[NBUCKET];
    __shared__ unsigned int csum[256];
    int t = threadIdx.x;
    unsigned int s = 0;
    for (int k = 0; k < NBUCKET/256; ++k) {
        unsigned int v = hist[t*(NBUCKET/256) + k];
        lh[t*(NBUCKET/256) + k] = v;
        s += v;
    }
    csum[t] = s;
    __syncthreads();
    /* inclusive suffix sum of csum */
    for (int off = 1; off < 256; off <<= 1) {
        unsigned int v = (t + off < 256) ? csum[t + off] : 0u;
        __syncthreads();
        csum[t] += v;
        __syncthreads();
    }
    unsigned int incl = csum[t];
    unsigned int excl = (t + 1 < 256) ? csum[t + 1] : 0u;
    if (incl >= KMAX && excl < KMAX) {
        unsigned int cum = excl;
        int cut = t * (NBUCKET/256);
        for (int b = t*(NBUCKET/256) + (NBUCKET/256) - 1; b >= t*(NBUCKET/256); --b) {
            cum += lh[b];
            if (cum >= KMAX) { cut = b; break; }
        }
        counters[2] = (unsigned int)cut;
    }
}

__global__ __launch_bounds__(256) void k_collect(
    const unsigned long long* __restrict__ keys,
    unsigned long long* __restrict__ cand,
    unsigned int* __restrict__ counters)
{
    unsigned int M   = counters[0];
    unsigned int cut = counters[2];
    for (unsigned int i = blockIdx.x * 256 + threadIdx.x; i < M; i += gridDim.x * 256) {
        unsigned long long k = keys[i];
        unsigned int sb = (unsigned int)(k >> 32);
        unsigned int bucket = (sb - BITS_LO) >> BUCKET_SHIFT;
        if (bucket > NBUCKET - 1u) bucket = NBUCKET - 1u;
        if (bucket >= cut) {
            unsigned int p = atomicAdd(&counters[1], 1u);
            if (p < CAND_CAP) cand[p] = k;
        }
    }
}

__global__ __launch_bounds__(1024) void k_final(
    const unsigned long long* __restrict__ cand,
    const unsigned int* __restrict__ counters,
    const int* __restrict__ cb, const int* __restrict__ cx,
    const int* __restrict__ cy, const int* __restrict__ cz,
    float* __restrict__ out)
{
    __shared__ unsigned long long sk[CAND_CAP];
    int t = threadIdx.x;
    unsigned int C = counters[1];
    if (C > CAND_CAP) C = CAND_CAP;
    for (int k = t; k < CAND_CAP; k += 1024) sk[k] = (k < (int)C) ? cand[k] : 0ull;
    __syncthreads();

    /* bitonic sort descending */
    for (int k = 2; k <= CAND_CAP; k <<= 1) {
        for (int j = k >> 1; j > 0; j >>= 1) {
            for (int i = t; i < CAND_CAP; i += 1024) {
                int ixj = i ^ j;
                if (ixj > i) {
                    unsigned long long a = sk[i], b = sk[ixj];
                    bool up = ((i & k) == 0);     /* up-region: keep larger at i (descending) */
                    if (up ? (a < b) : (a > b)) { sk[i] = b; sk[ixj] = a; }
                }
            }
            __syncthreads();
        }
    }

    if (t < KMAX) {
        unsigned long long k = sk[t];
        float val; int idx;
        if (k != 0ull) {
            idx = (int)(~(unsigned int)(k & 0xFFFFFFFFull));
            val = __uint_as_float((unsigned int)(k >> 32));
        } else {
            idx = t;        /* unreachable in practice (peaks >> 128) */
            val = -1.0f;
        }
        out[N_PTS + t]         = (float)idx;
        out[N_PTS + KMAX + t]  = val;
        float* pc = out + N_PTS + 2*KMAX + 4*t;
        pc[0] = (float)cb[idx]; pc[1] = (float)cx[idx];
        pc[2] = (float)cy[idx]; pc[3] = (float)cz[idx];
    }
}

extern "C" void kernel_launch(void* const* d_in, const int* in_sizes, int n_in,
                              void* d_out, int out_size, void* d_ws, size_t ws_size,
                              hipStream_t stream) {
    const float* feats = (const float*)d_in[0];
    const int*   cb    = (const int*)d_in[1];
    const int*   cx    = (const int*)d_in[2];
    const int*   cy    = (const int*)d_in[3];
    const int*   cz    = (const int*)d_in[4];
    const int*   mask  = (const int*)d_in[5];
    const float* W1    = (const float*)d_in[6];
    const float* b1    = (const float*)d_in[7];
    const float* W2    = (const float*)d_in[8];
    const float* b2    = (const float*)d_in[9];
    float* out = (float*)d_out;

    char* ws = (char*)d_ws;
    unsigned int*       grid     = (unsigned int*)(ws);
    unsigned int*       hist     = (unsigned int*)(ws + HIST_OFF);
    unsigned int*       counters = (unsigned int*)(ws + CNT_OFF);
    unsigned long long* keys     = (unsigned long long*)(ws + KEYS_OFF);
    unsigned long long* cand     = (unsigned long long*)(ws + CAND_OFF);

    /* clear grid + hist + counters (grid cleared to 0 == "-inf" in positive-float uint encoding) */
    hipMemsetAsync(ws, 0, CLEAR_BYTES, stream);

    k_detect_mask<<<1, 64, 0, stream>>>((const int*)mask, counters);

    int nb = (N_PTS + 255) / 256;
    k_mlp<<<nb, 256, 0, stream>>>(feats, cb, cx, cy, cz, mask,
                                  W1, b1, W2, b2, out, grid, counters);
    k_peak<<<nb, 256, 0, stream>>>(out, cb, cx, cy, cz, grid, keys, counters, hist);
    k_cutoff<<<1, 256, 0, stream>>>(hist, counters);
    k_collect<<<512, 256, 0, stream>>>(keys, cand, counters);
    k_final<<<1, 1024, 0, stream>>>(cand, counters, cb, cx, cy, cz, out);
}

// Round 2
// 701.568 us; speedup vs baseline: 1.0488x; 1.0488x over previous
//
#include <hip/hip_runtime.h>
#include <stdint.h>

#define N_PTS 1000000
#define FIN   64
#define HID   32
#define GB    2
#define GX    512
#define GY    512
#define GZ    64
#define KMAX  128
#define NBUCKET 4096
#define BITS_LO 0x3E4CCCCDu   /* bits of 0.2f */
#define BUCKET_SHIFT 13
#define CAND_CAP 4096

/* ---- workspace layout ----
 * [bitmap 4 MB | hist 16 KB | counters 64 B | (pad) | grid 134 MB (UNCLEARED) | keys 8 MB | cand 32 KB]
 * The grid is never memset: a cell is only read if its bitmap bit is set,
 * which implies at least one signed atomicMax with a positive value already
 * happened. The harness poisons ws to 0xAA bytes = 0xAAAAAAAA = negative
 * int32, which loses to any positive score-bit value under signed max.
 */
#define BM_WORDS   (GB*GX*GY)                 /* 524288 */
#define BM_BYTES   ((size_t)BM_WORDS*8)       /* 4,194,304 */
#define HIST_OFF   BM_BYTES
#define HIST_BYTES (NBUCKET*4)
#define CNT_OFF    (HIST_OFF + HIST_BYTES)
#define CNT_BYTES  64
#define CLEAR_BYTES (CNT_OFF + CNT_BYTES)     /* 4,210,752 */
#define GRID_OFF   ((size_t)4214784)          /* 4096-aligned, >= CLEAR_BYTES */
#define GRID_CELLS ((size_t)GB*GX*GY*GZ)      /* 33,554,432 */
#define GRID_BYTES (GRID_CELLS*4)             /* 134,217,728 */
#define KEYS_OFF   (GRID_OFF + GRID_BYTES)
#define CAND_OFF   (KEYS_OFF + (size_t)N_PTS*8)

/* counters: [0]=peak count M, [1]=collect count C, [2]=cutoff bucket, [3]=mask-is-bytes flag */

__global__ void k_detect_mask(const int* __restrict__ mask_i, unsigned int* __restrict__ counters) {
    if (threadIdx.x == 0 && blockIdx.x == 0) {
        unsigned int flag = 0;
        for (int k = 0; k < 256; ++k) {
            unsigned int v = (unsigned int)mask_i[k];
            if (v > 1u) flag = 1u;
        }
        counters[3] = flag;
    }
}

__global__ __launch_bounds__(256) void k_mlp(
    const float* __restrict__ feats,
    const int* __restrict__ cb, const int* __restrict__ cx,
    const int* __restrict__ cy, const int* __restrict__ cz,
    const int* __restrict__ mask_i,
    const float* __restrict__ W1, const float* __restrict__ b1,
    const float* __restrict__ W2, const float* __restrict__ b2,
    float* __restrict__ score_out, int* __restrict__ grid,
    unsigned long long* __restrict__ bm,
    const unsigned int* __restrict__ counters)
{
    int i = blockIdx.x * 256 + threadIdx.x;
    if (i >= N_PTS) return;

    float f[FIN];
    const float4* rp = (const float4*)(feats + (size_t)i * FIN);
#pragma unroll
    for (int q = 0; q < FIN / 4; ++q) {
        float4 v = rp[q];
        f[4*q+0] = v.x; f[4*q+1] = v.y; f[4*q+2] = v.z; f[4*q+3] = v.w;
    }

    float hj[HID];
#pragma unroll
    for (int j = 0; j < HID; ++j) hj[j] = b1[j];

#pragma unroll 4
    for (int k = 0; k < FIN; ++k) {
        float fk = f[k];
#pragma unroll
        for (int j = 0; j < HID; ++j) hj[j] = fmaf(fk, W1[k*HID + j], hj[j]);
    }

    float x = b2[0];
#pragma unroll
    for (int j = 0; j < HID; ++j) x += fmaxf(hj[j], 0.0f) * W2[j];

    float s = 1.0f / (1.0f + expf(-x));

    unsigned int mflag = counters[3];
    bool mk;
    if (mflag) mk = ((const unsigned char*)mask_i)[i] != 0;
    else       mk = mask_i[i] != 0;
    if (!mk) s = 0.0f;

    score_out[i] = s;

    if (s > 0.1f) {
        int sb = (int)__float_as_uint(s);   /* positive: 0x3DCC.. - 0x3F80.. */
        int b = cb[i], xx = cx[i], yy = cy[i], zz = cz[i];
        int col = (b*GX + xx)*GY + yy;
        atomicOr(&bm[col], 1ull << zz);
        atomicMax(&grid[((size_t)col << 6) + (size_t)zz], sb);
    }
}

__global__ __launch_bounds__(256) void k_peak(
    const float* __restrict__ s_buf,
    const int* __restrict__ cb, const int* __restrict__ cx,
    const int* __restrict__ cy, const int* __restrict__ cz,
    const int* __restrict__ grid,
    const unsigned long long* __restrict__ bm,
    unsigned long long* __restrict__ keys,
    unsigned int* __restrict__ counters,
    unsigned int* __restrict__ hist)
{
    int i = blockIdx.x * 256 + threadIdx.x;
    if (i >= N_PTS) return;
    float s = s_buf[i];
    if (!(s > 0.2f)) return;
    int sb = (int)__float_as_uint(s);
    int b = cb[i], x = cx[i], y = cy[i], z = cz[i];
    int z0 = (z > 0) ? z - 1 : 0;
    int z1 = (z < GZ-1) ? z + 1 : GZ-1;
    unsigned wmask = (1u << (z1 - z0 + 1)) - 1u;

    /* gather up to 9 bitmap column words (L2-resident 4 MB bitmap) */
    int cols[9]; unsigned long long w[9]; int ncol = 0;
#pragma unroll
    for (int dx = -1; dx <= 1; ++dx) {
        int xx = x + dx;
        if ((unsigned)xx >= (unsigned)GX) continue;
        int rowbase = (b*GX + xx)*GY;
#pragma unroll
        for (int dy = -1; dy <= 1; ++dy) {
            int yy = y + dy;
            if ((unsigned)yy >= (unsigned)GY) continue;
            cols[ncol++] = rowbase + yy;
        }
    }
    for (int c = 0; c < ncol; ++c) w[c] = bm[cols[c]];

    /* only touch the (uncleared!) grid where the bitmap says occupied */
    bool peak = true;
    for (int c = 0; c < ncol && peak; ++c) {
        unsigned win = (unsigned)(w[c] >> z0) & wmask;
        while (win) {
            int t = __ffs(win) - 1;
            win &= (win - 1u);
            int v = grid[((size_t)cols[c] << 6) + (size_t)(z0 + t)];
            if (v > sb) { peak = false; break; }
        }
    }
    if (!peak) return;

    unsigned int pos = atomicAdd(&counters[0], 1u);
    keys[pos] = ((unsigned long long)(unsigned int)sb << 32) | (unsigned int)(~(unsigned int)i);
    unsigned int bucket = ((unsigned int)sb - BITS_LO) >> BUCKET_SHIFT;
    if (bucket > NBUCKET - 1u) bucket = NBUCKET - 1u;
    atomicAdd(&hist[bucket], 1u);
}

__global__ __launch_bounds__(256) void k_cutoff(
    const unsigned int* __restrict__ hist, unsigned int* __restrict__ counters)
{
    __shared__ unsigned int lh[NBUCKET];
    __shared__ unsigned int csum[256];
    int t = threadIdx.x;
    unsigned int s = 0;
    for (int k = 0; k < NBUCKET/256; ++k) {
        unsigned int v = hist[t*(NBUCKET/256) + k];
        lh[t*(NBUCKET/256) + k] = v;
        s += v;
    }
    csum[t] = s;
    __syncthreads();
    /* inclusive suffix sum of csum */
    for (int off = 1; off < 256; off <<= 1) {
        unsigned int v = (t + off < 256) ? csum[t + off] : 0u;
        __syncthreads();
        csum[t] += v;
        __syncthreads();
    }
    unsigned int incl = csum[t];
    unsigned int excl = (t + 1 < 256) ? csum[t + 1] : 0u;
    if (incl >= KMAX && excl < KMAX) {
        unsigned int cum = excl;
        int cut = t * (NBUCKET/256);
        for (int b = t*(NBUCKET/256) + (NBUCKET/256) - 1; b >= t*(NBUCKET/256); --b) {
            cum += lh[b];
            if (cum >= KMAX) { cut = b; break; }
        }
        counters[2] = (unsigned int)cut;
    }
}

__global__ __launch_bounds__(256) void k_collect(
    const unsigned long long* __restrict__ keys,
    unsigned long long* __restrict__ cand,
    unsigned int* __restrict__ counters)
{
    unsigned int M   = counters[0];
    unsigned int cut = counters[2];
    for (unsigned int i = blockIdx.x * 256 + threadIdx.x; i < M; i += gridDim.x * 256) {
        unsigned long long k = keys[i];
        unsigned int sb = (unsigned int)(k >> 32);
        unsigned int bucket = (sb - BITS_LO) >> BUCKET_SHIFT;
        if (bucket > NBUCKET - 1u) bucket = NBUCKET - 1u;
        if (bucket >= cut) {
            unsigned int p = atomicAdd(&counters[1], 1u);
            if (p < CAND_CAP) cand[p] = k;
        }
    }
}

__global__ __launch_bounds__(1024) void k_final(
    const unsigned long long* __restrict__ cand,
    const unsigned int* __restrict__ counters,
    const int* __restrict__ cb, const int* __restrict__ cx,
    const int* __restrict__ cy, const int* __restrict__ cz,
    float* __restrict__ out)
{
    __shared__ unsigned long long sk[CAND_CAP];
    int t = threadIdx.x;
    unsigned int C = counters[1];
    if (C > CAND_CAP) C = CAND_CAP;
    for (int k = t; k < CAND_CAP; k += 1024) sk[k] = (k < (int)C) ? cand[k] : 0ull;
    __syncthreads();

    /* bitonic sort descending */
    for (int k = 2; k <= CAND_CAP; k <<= 1) {
        for (int j = k >> 1; j > 0; j >>= 1) {
            for (int i = t; i < CAND_CAP; i += 1024) {
                int ixj = i ^ j;
                if (ixj > i) {
                    unsigned long long a = sk[i], b = sk[ixj];
                    bool up = ((i & k) == 0);
                    if (up ? (a < b) : (a > b)) { sk[i] = b; sk[ixj] = a; }
                }
            }
            __syncthreads();
        }
    }

    if (t < KMAX) {
        unsigned long long k = sk[t];
        float val; int idx;
        if (k != 0ull) {
            idx = (int)(~(unsigned int)(k & 0xFFFFFFFFull));
            val = __uint_as_float((unsigned int)(k >> 32));
        } else {
            idx = t;
            val = -1.0f;
        }
        out[N_PTS + t]         = (float)idx;
        out[N_PTS + KMAX + t]  = val;
        float* pc = out + N_PTS + 2*KMAX + 4*t;
        pc[0] = (float)cb[idx]; pc[1] = (float)cx[idx];
        pc[2] = (float)cy[idx]; pc[3] = (float)cz[idx];
    }
}

extern "C" void kernel_launch(void* const* d_in, const int* in_sizes, int n_in,
                              void* d_out, int out_size, void* d_ws, size_t ws_size,
                              hipStream_t stream) {
    const float* feats = (const float*)d_in[0];
    const int*   cb    = (const int*)d_in[1];
    const int*   cx    = (const int*)d_in[2];
    const int*   cy    = (const int*)d_in[3];
    const int*   cz    = (const int*)d_in[4];
    const int*   mask  = (const int*)d_in[5];
    const float* W1    = (const float*)d_in[6];
    const float* b1    = (const float*)d_in[7];
    const float* W2    = (const float*)d_in[8];
    const float* b2    = (const float*)d_in[9];
    float* out = (float*)d_out;

    char* ws = (char*)d_ws;
    unsigned long long* bm       = (unsigned long long*)(ws);
    unsigned int*       hist     = (unsigned int*)(ws + HIST_OFF);
    unsigned int*       counters = (unsigned int*)(ws + CNT_OFF);
    int*                grid     = (int*)(ws + GRID_OFF);
    unsigned long long* keys     = (unsigned long long*)(ws + KEYS_OFF);
    unsigned long long* cand     = (unsigned long long*)(ws + CAND_OFF);

    /* clear ONLY bitmap + hist + counters (~4.2 MB). Grid is gated by the
       bitmap and needs no clear (0xAA poison is negative under signed max). */
    hipMemsetAsync(ws, 0, CLEAR_BYTES, stream);

    k_detect_mask<<<1, 64, 0, stream>>>((const int*)mask, counters);

    int nb = (N_PTS + 255) / 256;
    k_mlp<<<nb, 256, 0, stream>>>(feats, cb, cx, cy, cz, mask,
                                  W1, b1, W2, b2, out, grid, bm, counters);
    k_peak<<<nb, 256, 0, stream>>>(out, cb, cx, cy, cz, grid, bm, keys, counters, hist);
    k_cutoff<<<1, 256, 0, stream>>>(hist, counters);
    k_collect<<<512, 256, 0, stream>>>(keys, cand, counters);
    k_final<<<1, 1024, 0, stream>>>(cand, counters, cb, cx, cy, cz, out);
}

// Round 3
// 586.172 us; speedup vs baseline: 1.2553x; 1.1969x over previous
//
#include <hip/hip_runtime.h>
#include <stdint.h>

#define N_PTS 1000000
#define FIN   64
#define HID   32
#define GB    2
#define GX    512
#define GY    512
#define GZ    64
#define KMAX  128
#define NBUCKET 4096
#define BITS_LO 0x3E4CCCCDu   /* bits of 0.2f */
#define BUCKET_SHIFT 13
#define CAND_CAP 4096

/* ---- workspace layout ----
 * [bitmap 4 MB | hist 16 KB | counters 64 B | (pad) | grid 134 MB (UNCLEARED) | keys 8 MB | cand 32 KB]
 * Grid is never memset: a cell is only read if its bitmap bit is set, which
 * implies a signed atomicMax with a positive value already happened; the
 * 0xAA ws poison is negative int32 and loses automatically.
 */
#define BM_WORDS   (GB*GX*GY)                 /* 524288 */
#define BM_BYTES   ((size_t)BM_WORDS*8)       /* 4,194,304 */
#define HIST_OFF   BM_BYTES
#define HIST_BYTES (NBUCKET*4)
#define CNT_OFF    (HIST_OFF + HIST_BYTES)
#define CNT_BYTES  64
#define CLEAR_BYTES (CNT_OFF + CNT_BYTES)
#define GRID_OFF   ((size_t)4214784)          /* 4096-aligned, >= CLEAR_BYTES */
#define GRID_CELLS ((size_t)GB*GX*GY*GZ)
#define GRID_BYTES (GRID_CELLS*4)
#define KEYS_OFF   (GRID_OFF + GRID_BYTES)
#define CAND_OFF   (KEYS_OFF + (size_t)N_PTS*8)

/* counters: [0]=peak count M, [1]=collect count C, [2]=cutoff bucket, [3]=mask-is-bytes flag */

__global__ void k_detect_mask(const int* __restrict__ mask_i, unsigned int* __restrict__ counters) {
    /* 256 threads, one load each: int32-read of byte-packed bools shows values >1 */
    unsigned int v = (unsigned int)mask_i[threadIdx.x];
    if (v > 1u) atomicOr(&counters[3], 1u);
}

__global__ __launch_bounds__(256) void k_mlp(
    const float* __restrict__ feats,
    const int* __restrict__ cb, const int* __restrict__ cx,
    const int* __restrict__ cy, const int* __restrict__ cz,
    const int* __restrict__ mask_i,
    const float* __restrict__ W1, const float* __restrict__ b1,
    const float* __restrict__ W2, const float* __restrict__ b2,
    float* __restrict__ score_out, int* __restrict__ grid,
    unsigned long long* __restrict__ bm,
    const unsigned int* __restrict__ counters)
{
    int i = blockIdx.x * 256 + threadIdx.x;
    if (i >= N_PTS) return;

    unsigned int mflag = counters[3];
    bool mk;
    if (mflag) mk = ((const unsigned char*)mask_i)[i] != 0;
    else       mk = mask_i[i] != 0;

    float s = 0.0f;
    if (mk) {
        /* no f[64] local array: stream float4 -> FMA directly (keeps VGPR ~50, no scratch) */
        float hj[HID];
#pragma unroll
        for (int j = 0; j < HID; ++j) hj[j] = b1[j];

        const float4* rp = (const float4*)(feats + (size_t)i * FIN);
#pragma unroll 4
        for (int q = 0; q < FIN / 4; ++q) {
            float4 v = rp[q];
            const float* w0 = W1 + (4*q + 0) * HID;
            const float* w1 = W1 + (4*q + 1) * HID;
            const float* w2 = W1 + (4*q + 2) * HID;
            const float* w3 = W1 + (4*q + 3) * HID;
#pragma unroll
            for (int j = 0; j < HID; ++j) {
                float acc = hj[j];
                acc = fmaf(v.x, w0[j], acc);
                acc = fmaf(v.y, w1[j], acc);
                acc = fmaf(v.z, w2[j], acc);
                acc = fmaf(v.w, w3[j], acc);
                hj[j] = acc;
            }
        }

        float x = b2[0];
#pragma unroll
        for (int j = 0; j < HID; ++j) x += fmaxf(hj[j], 0.0f) * W2[j];

        s = 1.0f / (1.0f + expf(-x));
    }

    score_out[i] = s;

    if (s > 0.1f) {
        int sb = (int)__float_as_uint(s);   /* positive float bits */
        int b = cb[i], xx = cx[i], yy = cy[i], zz = cz[i];
        int col = (b*GX + xx)*GY + yy;
        atomicOr(&bm[col], 1ull << zz);
        atomicMax(&grid[((size_t)col << 6) + (size_t)zz], sb);
    }
}

__global__ __launch_bounds__(256) void k_peak(
    const float* __restrict__ s_buf,
    const int* __restrict__ cb, const int* __restrict__ cx,
    const int* __restrict__ cy, const int* __restrict__ cz,
    const int* __restrict__ grid,
    const unsigned long long* __restrict__ bm,
    unsigned long long* __restrict__ keys,
    unsigned int* __restrict__ counters,
    unsigned int* __restrict__ hist)
{
    int i = blockIdx.x * 256 + threadIdx.x;
    if (i >= N_PTS) return;
    float s = s_buf[i];
    if (!(s > 0.2f)) return;
    int sb = (int)__float_as_uint(s);
    int b = cb[i], x = cx[i], y = cy[i], z = cz[i];
    int z0 = (z > 0) ? z - 1 : 0;
    int z1 = (z < GZ-1) ? z + 1 : GZ-1;
    unsigned wmask = (1u << (z1 - z0 + 1)) - 1u;

    /* clamped 3x3 columns: clamping duplicates an in-range column, which is
       harmless for a "no neighbor greater" predicate. Fully unrolled ->
       everything in VGPRs, no scratch. */
    int xm = (x > 0) ? x - 1 : 0;
    int xp = (x < GX-1) ? x + 1 : GX-1;
    int ym = (y > 0) ? y - 1 : 0;
    int yp = (y < GY-1) ? y + 1 : GY-1;
    int rb = b * GX;
    int c0 = (rb + xm) * GY, c1 = (rb + x) * GY, c2 = (rb + xp) * GY;
    int col0 = c0+ym, col1 = c0+y, col2 = c0+yp;
    int col3 = c1+ym, col4 = c1+y, col5 = c1+yp;
    int col6 = c2+ym, col7 = c2+y, col8 = c2+yp;

    unsigned long long w0 = bm[col0], w1 = bm[col1], w2 = bm[col2];
    unsigned long long w3 = bm[col3], w4 = bm[col4], w5 = bm[col5];
    unsigned long long w6 = bm[col6], w7 = bm[col7], w8 = bm[col8];

    bool peak = true;
#define CHK(WV, CL) do { \
        unsigned win = (unsigned)((WV) >> z0) & wmask; \
        while (win && peak) { \
            int t = __ffs(win) - 1; win &= win - 1u; \
            if (grid[((size_t)(CL) << 6) + (size_t)(z0 + t)] > sb) peak = false; \
        } \
    } while (0)
    CHK(w0, col0); CHK(w1, col1); CHK(w2, col2);
    CHK(w3, col3); CHK(w4, col4); CHK(w5, col5);
    CHK(w6, col6); CHK(w7, col7); CHK(w8, col8);
#undef CHK
    if (!peak) return;

    unsigned int pos = atomicAdd(&counters[0], 1u);
    keys[pos] = ((unsigned long long)(unsigned int)sb << 32) | (unsigned int)(~(unsigned int)i);
    unsigned int bucket = ((unsigned int)sb - BITS_LO) >> BUCKET_SHIFT;
    if (bucket > NBUCKET - 1u) bucket = NBUCKET - 1u;
    atomicAdd(&hist[bucket], 1u);
}

__global__ __launch_bounds__(256) void k_cutoff(
    const unsigned int* __restrict__ hist, unsigned int* __restrict__ counters)
{
    __shared__ unsigned int lh[NBUCKET];
    __shared__ unsigned int csum[256];
    int t = threadIdx.x;
    unsigned int s = 0;
    for (int k = 0; k < NBUCKET/256; ++k) {
        unsigned int v = hist[t*(NBUCKET/256) + k];
        lh[t*(NBUCKET/256) + k] = v;
        s += v;
    }
    csum[t] = s;
    __syncthreads();
    for (int off = 1; off < 256; off <<= 1) {
        unsigned int v = (t + off < 256) ? csum[t + off] : 0u;
        __syncthreads();
        csum[t] += v;
        __syncthreads();
    }
    unsigned int incl = csum[t];
    unsigned int excl = (t + 1 < 256) ? csum[t + 1] : 0u;
    if (incl >= KMAX && excl < KMAX) {
        unsigned int cum = excl;
        int cut = t * (NBUCKET/256);
        for (int b = t*(NBUCKET/256) + (NBUCKET/256) - 1; b >= t*(NBUCKET/256); --b) {
            cum += lh[b];
            if (cum >= KMAX) { cut = b; break; }
        }
        counters[2] = (unsigned int)cut;
    }
}

__global__ __launch_bounds__(256) void k_collect(
    const unsigned long long* __restrict__ keys,
    unsigned long long* __restrict__ cand,
    unsigned int* __restrict__ counters)
{
    unsigned int M   = counters[0];
    unsigned int cut = counters[2];
    for (unsigned int i = blockIdx.x * 256 + threadIdx.x; i < M; i += gridDim.x * 256) {
        unsigned long long k = keys[i];
        unsigned int sb = (unsigned int)(k >> 32);
        unsigned int bucket = (sb - BITS_LO) >> BUCKET_SHIFT;
        if (bucket > NBUCKET - 1u) bucket = NBUCKET - 1u;
        if (bucket >= cut) {
            unsigned int p = atomicAdd(&counters[1], 1u);
            if (p < CAND_CAP) cand[p] = k;
        }
    }
}

__global__ __launch_bounds__(1024) void k_final(
    const unsigned long long* __restrict__ cand,
    const unsigned int* __restrict__ counters,
    const int* __restrict__ cb, const int* __restrict__ cx,
    const int* __restrict__ cy, const int* __restrict__ cz,
    float* __restrict__ out)
{
    __shared__ unsigned long long sk[CAND_CAP];
    int t = threadIdx.x;
    unsigned int C = counters[1];
    if (C > CAND_CAP) C = CAND_CAP;
    /* adaptive pow2 size: typically ~256 instead of 4096 */
    int P = KMAX;
    while (P < (int)C) P <<= 1;
    for (int k = t; k < P; k += 1024) sk[k] = (k < (int)C) ? cand[k] : 0ull;
    __syncthreads();

    for (int k = 2; k <= P; k <<= 1) {
        for (int j = k >> 1; j > 0; j >>= 1) {
            for (int i = t; i < P; i += 1024) {
                int ixj = i ^ j;
                if (ixj > i) {
                    unsigned long long a = sk[i], b = sk[ixj];
                    bool up = ((i & k) == 0);
                    if (up ? (a < b) : (a > b)) { sk[i] = b; sk[ixj] = a; }
                }
            }
            __syncthreads();
        }
    }

    if (t < KMAX) {
        unsigned long long k = sk[t];
        float val; int idx;
        if (k != 0ull) {
            idx = (int)(~(unsigned int)(k & 0xFFFFFFFFull));
            val = __uint_as_float((unsigned int)(k >> 32));
        } else {
            idx = t;
            val = -1.0f;
        }
        out[N_PTS + t]         = (float)idx;
        out[N_PTS + KMAX + t]  = val;
        float* pc = out + N_PTS + 2*KMAX + 4*t;
        pc[0] = (float)cb[idx]; pc[1] = (float)cx[idx];
        pc[2] = (float)cy[idx]; pc[3] = (float)cz[idx];
    }
}

extern "C" void kernel_launch(void* const* d_in, const int* in_sizes, int n_in,
                              void* d_out, int out_size, void* d_ws, size_t ws_size,
                              hipStream_t stream) {
    const float* feats = (const float*)d_in[0];
    const int*   cb    = (const int*)d_in[1];
    const int*   cx    = (const int*)d_in[2];
    const int*   cy    = (const int*)d_in[3];
    const int*   cz    = (const int*)d_in[4];
    const int*   mask  = (const int*)d_in[5];
    const float* W1    = (const float*)d_in[6];
    const float* b1    = (const float*)d_in[7];
    const float* W2    = (const float*)d_in[8];
    const float* b2    = (const float*)d_in[9];
    float* out = (float*)d_out;

    char* ws = (char*)d_ws;
    unsigned long long* bm       = (unsigned long long*)(ws);
    unsigned int*       hist     = (unsigned int*)(ws + HIST_OFF);
    unsigned int*       counters = (unsigned int*)(ws + CNT_OFF);
    int*                grid     = (int*)(ws + GRID_OFF);
    unsigned long long* keys     = (unsigned long long*)(ws + KEYS_OFF);
    unsigned long long* cand     = (unsigned long long*)(ws + CAND_OFF);

    hipMemsetAsync(ws, 0, CLEAR_BYTES, stream);

    k_detect_mask<<<1, 256, 0, stream>>>((const int*)mask, counters);

    int nb = (N_PTS + 255) / 256;
    k_mlp<<<nb, 256, 0, stream>>>(feats, cb, cx, cy, cz, mask,
                                  W1, b1, W2, b2, out, grid, bm, counters);
    k_peak<<<nb, 256, 0, stream>>>(out, cb, cx, cy, cz, grid, bm, keys, counters, hist);
    k_cutoff<<<1, 256, 0, stream>>>(hist, counters);
    k_collect<<<512, 256, 0, stream>>>(keys, cand, counters);
    k_final<<<1, 1024, 0, stream>>>(cand, counters, cb, cx, cy, cz, out);
}

// Round 4
// 583.260 us; speedup vs baseline: 1.2615x; 1.0050x over previous
//
#include <hip/hip_runtime.h>
#include <stdint.h>

#define N_PTS 1000000
#define FIN   64
#define HID   32
#define GB    2
#define GX    512
#define GY    512
#define GZ    64
#define KMAX  128
#define NBUCKET 4096
#define BITS_LO 0x3E4CCCCDu   /* bits of 0.2f */
#define BUCKET_SHIFT 13
#define CAND_CAP 4096

/* ---- workspace layout (identical footprint to R3: known to fit) ----
 * [bitmap 4 MB | hist 16 KB | counters 64 B | pad | grid 134 MB (UNCLEARED) | keys 8 MB | cand 32 KB]
 * Grid is never memset: a cell is only read if its bitmap bit is set, which
 * implies a signed atomicMax with a positive value already happened; the
 * 0xAA ws poison is negative int32 and loses automatically.
 */
#define BM_WORDS   (GB*GX*GY)
#define BM_BYTES   ((size_t)BM_WORDS*8)
#define HIST_OFF   BM_BYTES
#define HIST_BYTES (NBUCKET*4)
#define CNT_OFF    (HIST_OFF + HIST_BYTES)
#define CNT_BYTES  64
#define CLEAR_BYTES (CNT_OFF + CNT_BYTES)
#define GRID_OFF   ((size_t)4214784)
#define GRID_CELLS ((size_t)GB*GX*GY*GZ)
#define GRID_BYTES (GRID_CELLS*4)
#define KEYS_OFF   (GRID_OFF + GRID_BYTES)
#define CAND_OFF   (KEYS_OFF + (size_t)N_PTS*8)

/* counters: [0]=peak count M, [1]=collect count C */

__global__ __launch_bounds__(256) void k_mlp(
    const float* __restrict__ feats,
    const int* __restrict__ cb, const int* __restrict__ cx,
    const int* __restrict__ cy, const int* __restrict__ cz,
    const int* __restrict__ mask_i,
    const float* __restrict__ W1, const float* __restrict__ b1,
    const float* __restrict__ W2, const float* __restrict__ b2,
    float* __restrict__ score_out, int* __restrict__ grid,
    unsigned long long* __restrict__ bm)
{
    /* per-block mask-format detection: int32-read of byte-packed bools shows
       values >1 with overwhelming probability over 256 words; true int32
       0/1 data never does. Same 1 KB read by every block -> L2 broadcast. */
    __shared__ unsigned int s_mflag;
    if (threadIdx.x == 0) s_mflag = 0u;
    __syncthreads();
    {
        unsigned int v = (unsigned int)mask_i[threadIdx.x];
        if (v > 1u) atomicOr(&s_mflag, 1u);
    }
    __syncthreads();
    bool mask_is_bytes = (s_mflag != 0u);

    int i = blockIdx.x * 256 + threadIdx.x;
    if (i >= N_PTS) return;

    bool mk = mask_is_bytes ? (((const unsigned char*)mask_i)[i] != 0)
                            : (mask_i[i] != 0);

    float s = 0.0f;
    if (mk) {
        float hj[HID];
#pragma unroll
        for (int j = 0; j < HID; ++j) hj[j] = b1[j];

        const float4* rp = (const float4*)(feats + (size_t)i * FIN);
#pragma unroll 4
        for (int q = 0; q < FIN / 4; ++q) {
            float4 v = rp[q];
            const float* w0 = W1 + (4*q + 0) * HID;
            const float* w1 = W1 + (4*q + 1) * HID;
            const float* w2 = W1 + (4*q + 2) * HID;
            const float* w3 = W1 + (4*q + 3) * HID;
#pragma unroll
            for (int j = 0; j < HID; ++j) {
                float acc = hj[j];
                acc = fmaf(v.x, w0[j], acc);
                acc = fmaf(v.y, w1[j], acc);
                acc = fmaf(v.z, w2[j], acc);
                acc = fmaf(v.w, w3[j], acc);
                hj[j] = acc;
            }
        }

        float x = b2[0];
#pragma unroll
        for (int j = 0; j < HID; ++j) x += fmaxf(hj[j], 0.0f) * W2[j];

        s = 1.0f / (1.0f + expf(-x));
    }

    score_out[i] = s;

    if (s > 0.1f) {
        int sb = (int)__float_as_uint(s);   /* positive float bits */
        int b = cb[i], xx = cx[i], yy = cy[i], zz = cz[i];
        int col = (b*GX + xx)*GY + yy;
        atomicOr(&bm[col], 1ull << zz);          /* scattered: ok */
        atomicMax(&grid[((size_t)col << 6) + (size_t)zz], sb);
    }
}

__global__ __launch_bounds__(256) void k_peak(
    const float* __restrict__ s_buf,
    const int* __restrict__ cb, const int* __restrict__ cx,
    const int* __restrict__ cy, const int* __restrict__ cz,
    const int* __restrict__ grid,
    const unsigned long long* __restrict__ bm,
    unsigned long long* __restrict__ keys,
    unsigned int* __restrict__ counters,
    unsigned int* __restrict__ hist)
{
    int i = blockIdx.x * 256 + threadIdx.x;
    bool valid = (i < N_PTS);
    float s = 0.0f;
    if (valid) s = s_buf[i];
    bool cand = valid && (s > 0.2f);

    int  sb = (int)__float_as_uint(s);
    bool peak = false;
    unsigned int bucket = 0;

    if (cand) {
        int b = cb[i], x = cx[i], y = cy[i], z = cz[i];
        int z0 = (z > 0) ? z - 1 : 0;
        int z1 = (z < GZ-1) ? z + 1 : GZ-1;
        unsigned wmask = (1u << (z1 - z0 + 1)) - 1u;

        int xm = (x > 0) ? x - 1 : 0;
        int xp = (x < GX-1) ? x + 1 : GX-1;
        int ym = (y > 0) ? y - 1 : 0;
        int yp = (y < GY-1) ? y + 1 : GY-1;
        int rb = b * GX;
        int c0 = (rb + xm) * GY, c1 = (rb + x) * GY, c2 = (rb + xp) * GY;
        int col0 = c0+ym, col1 = c0+y, col2 = c0+yp;
        int col3 = c1+ym, col4 = c1+y, col5 = c1+yp;
        int col6 = c2+ym, col7 = c2+y, col8 = c2+yp;

        unsigned long long w0 = bm[col0], w1 = bm[col1], w2 = bm[col2];
        unsigned long long w3 = bm[col3], w4 = bm[col4], w5 = bm[col5];
        unsigned long long w6 = bm[col6], w7 = bm[col7], w8 = bm[col8];

        /* no early exit: the 9 column loops are mutually independent so the
           scattered grid loads can be in flight simultaneously */
        int vmax = (int)0x80000000;
#define CHK(WV, CL) do { \
            unsigned win = (unsigned)((WV) >> z0) & wmask; \
            while (win) { \
                int t = __ffs(win) - 1; win &= win - 1u; \
                int v = grid[((size_t)(CL) << 6) + (size_t)(z0 + t)]; \
                vmax = (v > vmax) ? v : vmax; \
            } \
        } while (0)
        CHK(w0, col0); CHK(w1, col1); CHK(w2, col2);
        CHK(w3, col3); CHK(w4, col4); CHK(w5, col5);
        CHK(w6, col6); CHK(w7, col7); CHK(w8, col8);
#undef CHK
        peak = (vmax <= sb);
        bucket = ((unsigned int)sb - BITS_LO) >> BUCKET_SHIFT;
        if (bucket > NBUCKET - 1u) bucket = NBUCKET - 1u;
    }

    /* wave-aggregated append: ONE same-address atomic per wave instead of
       one per peak lane (the per-lane version serialized ~200k RMWs at a
       single L2 bank and was the entire k_peak bottleneck) */
    unsigned long long bal = __ballot(peak ? 1 : 0);
    if (bal) {
        int lane = threadIdx.x & 63;
        int leader = __ffsll((long long)bal) - 1;
        unsigned int base = 0;
        if (lane == leader) base = atomicAdd(&counters[0], (unsigned int)__popcll(bal));
        base = __shfl(base, leader);
        if (peak) {
            unsigned int pos = base + (unsigned int)__popcll(bal & ((1ull << lane) - 1ull));
            keys[pos] = ((unsigned long long)(unsigned int)sb << 32) | (unsigned int)(~(unsigned int)i);
            atomicAdd(&hist[bucket], 1u);   /* scattered over 4096 buckets: ok */
        }
    }
}

/* fused cutoff+collect: every block redundantly computes the cutoff bucket
   from hist (16 KB, L2-hot), then grid-strides the keys array */
__global__ __launch_bounds__(256) void k_collect(
    const unsigned long long* __restrict__ keys,
    unsigned long long* __restrict__ cand,
    unsigned int* __restrict__ counters,
    const unsigned int* __restrict__ hist)
{
    __shared__ unsigned int lh[NBUCKET];
    __shared__ unsigned int csum[256];
    __shared__ unsigned int s_cut;
    int t = threadIdx.x;
    if (t == 0) s_cut = 0u;
    unsigned int ssum = 0;
    for (int k = 0; k < NBUCKET/256; ++k) {
        unsigned int v = hist[t*(NBUCKET/256) + k];
        lh[t*(NBUCKET/256) + k] = v;
        ssum += v;
    }
    csum[t] = ssum;
    __syncthreads();
    for (int off = 1; off < 256; off <<= 1) {
        unsigned int v = (t + off < 256) ? csum[t + off] : 0u;
        __syncthreads();
        csum[t] += v;
        __syncthreads();
    }
    unsigned int incl = csum[t];
    unsigned int excl = (t + 1 < 256) ? csum[t + 1] : 0u;
    if (incl >= KMAX && excl < KMAX) {
        unsigned int cum = excl;
        int cut = t * (NBUCKET/256);
        for (int b = t*(NBUCKET/256) + (NBUCKET/256) - 1; b >= t*(NBUCKET/256); --b) {
            cum += lh[b];
            if (cum >= KMAX) { cut = b; break; }
        }
        s_cut = (unsigned int)cut;
    }
    __syncthreads();
    unsigned int cut = s_cut;
    unsigned int M  = counters[0];

    for (unsigned int i = blockIdx.x * 256 + t; i < M; i += gridDim.x * 256) {
        unsigned long long k = keys[i];
        unsigned int sbu = (unsigned int)(k >> 32);
        unsigned int bucket = (sbu - BITS_LO) >> BUCKET_SHIFT;
        if (bucket > NBUCKET - 1u) bucket = NBUCKET - 1u;
        bool take = (bucket >= cut);
        unsigned long long bal = __ballot(take ? 1 : 0);
        if (bal) {
            int lane = threadIdx.x & 63;
            int leader = __ffsll((long long)bal) - 1;
            unsigned int base = 0;
            if (lane == leader) base = atomicAdd(&counters[1], (unsigned int)__popcll(bal));
            base = __shfl(base, leader);
            if (take) {
                unsigned int p = base + (unsigned int)__popcll(bal & ((1ull << lane) - 1ull));
                if (p < CAND_CAP) cand[p] = k;
            }
        }
    }
}

__global__ __launch_bounds__(1024) void k_final(
    const unsigned long long* __restrict__ cand,
    const unsigned int* __restrict__ counters,
    const int* __restrict__ cb, const int* __restrict__ cx,
    const int* __restrict__ cy, const int* __restrict__ cz,
    float* __restrict__ out)
{
    __shared__ unsigned long long sk[CAND_CAP];
    int t = threadIdx.x;
    unsigned int C = counters[1];
    if (C > CAND_CAP) C = CAND_CAP;
    int P = KMAX;
    while (P < (int)C) P <<= 1;
    for (int k = t; k < P; k += 1024) sk[k] = (k < (int)C) ? cand[k] : 0ull;
    __syncthreads();

    for (int k = 2; k <= P; k <<= 1) {
        for (int j = k >> 1; j > 0; j >>= 1) {
            for (int i = t; i < P; i += 1024) {
                int ixj = i ^ j;
                if (ixj > i) {
                    unsigned long long a = sk[i], b = sk[ixj];
                    bool up = ((i & k) == 0);
                    if (up ? (a < b) : (a > b)) { sk[i] = b; sk[ixj] = a; }
                }
            }
            __syncthreads();
        }
    }

    if (t < KMAX) {
        unsigned long long k = sk[t];
        float val; int idx;
        if (k != 0ull) {
            idx = (int)(~(unsigned int)(k & 0xFFFFFFFFull));
            val = __uint_as_float((unsigned int)(k >> 32));
        } else {
            idx = t;
            val = -1.0f;
        }
        out[N_PTS + t]         = (float)idx;
        out[N_PTS + KMAX + t]  = val;
        float* pc = out + N_PTS + 2*KMAX + 4*t;
        pc[0] = (float)cb[idx]; pc[1] = (float)cx[idx];
        pc[2] = (float)cy[idx]; pc[3] = (float)cz[idx];
    }
}

extern "C" void kernel_launch(void* const* d_in, const int* in_sizes, int n_in,
                              void* d_out, int out_size, void* d_ws, size_t ws_size,
                              hipStream_t stream) {
    const float* feats = (const float*)d_in[0];
    const int*   cb    = (const int*)d_in[1];
    const int*   cx    = (const int*)d_in[2];
    const int*   cy    = (const int*)d_in[3];
    const int*   cz    = (const int*)d_in[4];
    const int*   mask  = (const int*)d_in[5];
    const float* W1    = (const float*)d_in[6];
    const float* b1    = (const float*)d_in[7];
    const float* W2    = (const float*)d_in[8];
    const float* b2    = (const float*)d_in[9];
    float* out = (float*)d_out;

    char* ws = (char*)d_ws;
    unsigned long long* bm       = (unsigned long long*)(ws);
    unsigned int*       hist     = (unsigned int*)(ws + HIST_OFF);
    unsigned int*       counters = (unsigned int*)(ws + CNT_OFF);
    int*                grid     = (int*)(ws + GRID_OFF);
    unsigned long long* keys     = (unsigned long long*)(ws + KEYS_OFF);
    unsigned long long* cand     = (unsigned long long*)(ws + CAND_OFF);

    hipMemsetAsync(ws, 0, CLEAR_BYTES, stream);

    int nb = (N_PTS + 255) / 256;
    k_mlp<<<nb, 256, 0, stream>>>(feats, cb, cx, cy, cz, mask,
                                  W1, b1, W2, b2, out, grid, bm);
    k_peak<<<nb, 256, 0, stream>>>(out, cb, cx, cy, cz, grid, bm, keys, counters, hist);
    k_collect<<<512, 256, 0, stream>>>(keys, cand, counters, hist);
    k_final<<<1, 1024, 0, stream>>>(cand, counters, cb, cx, cy, cz, out);
}